// Round 21
// baseline (273.987 us; speedup 1.0000x reference)
//
#include <hip/hip_runtime.h>
#include <hip/hip_bf16.h>
#include <math.h>

typedef __bf16 bf16_t;
typedef __bf16 bf16x8 __attribute__((ext_vector_type(8)));
typedef __bf16 bf16x2 __attribute__((ext_vector_type(2)));
typedef float f32x4 __attribute__((ext_vector_type(4)));
typedef unsigned int u32;
typedef u32 u32x4 __attribute__((ext_vector_type(4)));
typedef u32 u32x2 __attribute__((ext_vector_type(2)));

#define MFMA16(a,b,c) __builtin_amdgcn_mfma_f32_16x16x32_bf16((a),(b),(c),0,0,0)

// async global->LDS, 16B per lane; LDS dest = wave-uniform base + lane*16
__device__ __forceinline__ void gload_lds16(const bf16_t* g, bf16_t* l) {
  __builtin_amdgcn_global_load_lds(
      (const __attribute__((address_space(1))) void*)g,
      (__attribute__((address_space(3))) void*)l, 16, 0, 0);
}

// ---------------- fp32 -> bf16 flat convert (8/thread) ----------------
__global__ void k_cvt(const float* __restrict__ in, bf16_t* __restrict__ out, int n) {
  int i = (blockIdx.x * blockDim.x + threadIdx.x) * 8;
  int stride = gridDim.x * blockDim.x * 8;
  for (; i < n; i += stride) {
    float4 a = *(const float4*)&in[i];
    float4 b = *(const float4*)&in[i + 4];
    bf16x8 o;
    o[0] = (bf16_t)a.x; o[1] = (bf16_t)a.y; o[2] = (bf16_t)a.z; o[3] = (bf16_t)a.w;
    o[4] = (bf16_t)b.x; o[5] = (bf16_t)b.y; o[6] = (bf16_t)b.z; o[7] = (bf16_t)b.w;
    *(bf16x8*)&out[i] = o;
  }
}

// ---------------- fp32 [R][C] -> bf16 [C][R] transpose-convert ----------------
__global__ void k_transpose_cvt(const float* __restrict__ in, bf16_t* __restrict__ out,
                                int R, int C) {
  __shared__ float tile[32][33];
  int c0 = blockIdx.x * 32, r0 = blockIdx.y * 32;
  int x = threadIdx.x, y = threadIdx.y;  // block (32,8)
#pragma unroll
  for (int i = 0; i < 32; i += 8) tile[y + i][x] = in[(size_t)(r0 + y + i) * C + c0 + x];
  __syncthreads();
#pragma unroll
  for (int i = 0; i < 32; i += 8)
    out[(size_t)(c0 + y + i) * R + r0 + x] = (bf16_t)tile[x][y + i];
}

// ---------------- RoPE cos/sin table: [2048][16] each ----------------
__global__ void k_sincos(float* __restrict__ ct, float* __restrict__ st) {
  int idx = blockIdx.x * blockDim.x + threadIdx.x;  // 0..32767
  int pos = idx >> 4, i = idx & 15;
  float invf = powf(10000.0f, -(float)i / 16.0f);
  float ang = (float)pos * invf;
  ct[idx] = cosf(ang);
  st[idx] = sinf(ang);
}

// ======== 128x128-tile 2-phase GEMM, r21: A triple-buffered, vmcnt(8) deep pipeline ========
// 4 waves, LDS 80KB (A[3]@0/16K/32K, B[2]@48K/64K) -> 2 blk/CU (2x80=160KB exact).
// Per tile t: ph0 {16 frag reads (A(t),B(t)); stageA(t+2)->(t+2)%3; MFMA m0,m1; BAR}
//             ph1 {stageB(t+2)->(t+2)&1; MFMA m2,m3; vmcnt(8); BAR}
// vmcnt(8) completes tile t-1's A(t+1),B(t+1) (each tile issues 8 loads) -- loads now
// have a FULL tile (~2x) of compute to cover latency vs r20's vmcnt(4).
// Hazards: A buf (t+2)%3 != t%3; prior content A(t-1) consumed before t-1's barriers.
// B two-buffer: B(t) frags all read in ph0 before the barrier preceding stageB(t+2).
template <int N, int K, int EPI, bool OUT_F32>
__global__ __launch_bounds__(256, 2) void k_gemm256(const bf16_t* __restrict__ A,
                                                    const bf16_t* __restrict__ Bt,
                                                    const float* __restrict__ bias,
                                                    void* __restrict__ C0,
                                                    bf16_t* __restrict__ C1,
                                                    bf16_t* __restrict__ C2,
                                                    const float* __restrict__ ct,
                                                    const float* __restrict__ st) {
  extern __shared__ char smem[];  // 81920 bytes
  const int tid = threadIdx.x, lane = tid & 63, w = tid >> 6;
  const int lane15 = lane & 15, g = lane >> 4;
  const int wr = w >> 1, wc = w & 1;
  const int rowBase = blockIdx.y * 128, colBase = blockIdx.x * 128;
  constexpr int NT = K / 64;
  const int srow = lane >> 3;            // 0..7 row within 8-row stripe
  const int schunk = (lane & 7) ^ srow;  // pre-swizzled source chunk
  const int rdswz = (lane15 & 7) << 4;   // read-side swizzle

  auto stageA = [&](int t, int buf) {  // A tile 128x64: 4 wave-loads (8 rows each)
    const bf16_t* gb = A + (size_t)rowBase * K + t * 64;
    char* lb = smem + buf * 16384;
#pragma unroll
    for (int i = 0; i < 4; ++i) {
      int r0 = (w * 4 + i) * 8;
      gload_lds16(gb + (size_t)(r0 + srow) * K + schunk * 8, (bf16_t*)(lb + r0 * 128));
    }
  };
  auto stageB = [&](int t) {  // B tile 128x64: 4 wave-loads
    const bf16_t* gb = Bt + (size_t)colBase * K + t * 64;
    char* lb = smem + 49152 + (t & 1) * 16384;
#pragma unroll
    for (int i = 0; i < 4; ++i) {
      int r0 = (w * 4 + i) * 8;
      gload_lds16(gb + (size_t)(r0 + srow) * K + schunk * 8, (bf16_t*)(lb + r0 * 128));
    }
  };

  f32x4 acc[4][4] = {};
  // prologue: B(0), A(0), B(1), A(1) [16 loads]; vmcnt(8) -> B(0),A(0) complete
  stageB(0); stageA(0, 0);
  stageB(1); stageA(1, 1);
  asm volatile("s_waitcnt vmcnt(8)" ::: "memory");
  __builtin_amdgcn_sched_barrier(0);
  __builtin_amdgcn_s_barrier();

  int abuf = 0;  // t % 3
  for (int t = 0; t < NT; ++t) {
    const char* ab = smem + abuf * 16384;
    const char* bb = smem + 49152 + (t & 1) * 16384;
    bf16x8 bfr[4][2], af[4][2];
    // ---- phase 0: ALL frag reads (8 B + 8 A); stage A(t+2); MFMA m0,m1; BAR ----
#pragma unroll
    for (int n = 0; n < 4; ++n)
#pragma unroll
      for (int kk = 0; kk < 2; ++kk)
        bfr[n][kk] = *(const bf16x8*)(bb + (wc * 64 + n * 16 + lane15) * 128 +
                                      ((kk * 64 + g * 16) ^ rdswz));
#pragma unroll
    for (int mi = 0; mi < 4; ++mi)
#pragma unroll
      for (int kk = 0; kk < 2; ++kk)
        af[mi][kk] = *(const bf16x8*)(ab + (wr * 64 + mi * 16 + lane15) * 128 +
                                      ((kk * 64 + g * 16) ^ rdswz));
    if (t + 2 < NT) {
      int nb = abuf + 2;
      if (nb >= 3) nb -= 3;
      stageA(t + 2, nb);
    }
    __builtin_amdgcn_s_setprio(1);
#pragma unroll
    for (int mi = 0; mi < 2; ++mi)
#pragma unroll
      for (int n = 0; n < 4; ++n)
#pragma unroll
        for (int kk = 0; kk < 2; ++kk)
          acc[mi][n] = MFMA16(af[mi][kk], bfr[n][kk], acc[mi][n]);
    __builtin_amdgcn_s_setprio(0);
    __builtin_amdgcn_s_barrier();
    // ---- phase 1: stage B(t+2); MFMA m2,m3; vmcnt(8); BAR ----
    if (t + 2 < NT) stageB(t + 2);
    __builtin_amdgcn_s_setprio(1);
#pragma unroll
    for (int mi = 2; mi < 4; ++mi)
#pragma unroll
      for (int n = 0; n < 4; ++n)
#pragma unroll
        for (int kk = 0; kk < 2; ++kk)
          acc[mi][n] = MFMA16(af[mi][kk], bfr[n][kk], acc[mi][n]);
    __builtin_amdgcn_s_setprio(0);
    if (t + 2 < NT) {
      asm volatile("s_waitcnt vmcnt(8)" ::: "memory");
    } else {
      asm volatile("s_waitcnt vmcnt(0)" ::: "memory");
    }
    __builtin_amdgcn_sched_barrier(0);
    __builtin_amdgcn_s_barrier();
    abuf = (abuf == 2) ? 0 : abuf + 1;
  }

  if constexpr (EPI == 0) {
#pragma unroll
    for (int m = 0; m < 4; ++m)
#pragma unroll
      for (int n = 0; n < 4; ++n) {
        int ccol = colBase + wc * 64 + n * 16 + lane15;
        float bb2 = bias[ccol];
#pragma unroll
        for (int j = 0; j < 4; ++j) {
          int crow = rowBase + wr * 64 + m * 16 + g * 4 + j;
          if constexpr (OUT_F32)
            ((float*)C0)[(size_t)crow * N + ccol] = acc[m][n][j] + bb2;
          else
            ((bf16_t*)C0)[(size_t)crow * N + ccol] = (bf16_t)(acc[m][n][j] + bb2);
        }
      }
  } else {
    const int colb = colBase + wc * 64;
    const int which = colb >> 11;  // 0=q 1=k 2=v (wave-uniform)
    const int h = (colb >> 6) & 31;
    float bb2[4];
#pragma unroll
    for (int n = 0; n < 4; ++n) bb2[n] = bias[colb + n * 16 + lane15];
    if (which < 2) {
      // q/k: rope + row-major store [bh][s][64]
      bf16_t* dst = which == 0 ? (bf16_t*)C0 : C1;
#pragma unroll
      for (int m = 0; m < 4; ++m)
#pragma unroll
        for (int j = 0; j < 4; ++j) {
          int row = rowBase + wr * 64 + m * 16 + g * 4 + j;
          int s = row & 2047, b = row >> 11;
          float v[4];
#pragma unroll
          for (int n = 0; n < 4; ++n) v[n] = acc[m][n][j] + bb2[n];
          float c = ct[s * 16 + lane15], sn = st[s * 16 + lane15];
          float a = v[0], b2 = v[1];
          v[0] = a * c - b2 * sn;
          v[1] = a * sn + b2 * c;
          bf16_t* drow = dst + ((size_t)(b * 32 + h) * 2048 + s) * 64;
#pragma unroll
          for (int n = 0; n < 4; ++n) drow[n * 16 + lane15] = (bf16_t)v[n];
        }
    } else {
      // V: transpose via per-wave private LDS tile [64 d][68 s], write vT [bh][64][2048]
      bf16_t* tb = (bf16_t*)(smem + w * 8704);
#pragma unroll
      for (int m = 0; m < 4; ++m)
#pragma unroll
        for (int j = 0; j < 4; ++j) {
          int sl = m * 16 + g * 4 + j;
#pragma unroll
          for (int n = 0; n < 4; ++n)
            tb[(n * 16 + lane15) * 68 + sl] = (bf16_t)(acc[m][n][j] + bb2[n]);
        }
      asm volatile("s_waitcnt lgkmcnt(0)" ::: "memory");
      __builtin_amdgcn_sched_barrier(0);
      const int row0 = rowBase + wr * 64;  // 64-row range never crosses batch boundary
      const int s0 = row0 & 2047, b = row0 >> 11;
      const size_t obase = (size_t)(b * 32 + h) * 64 * 2048;
#pragma unroll
      for (int i = 0; i < 16; ++i) {
        int d = i * 4 + (lane >> 4);
        int so = lane15 * 4;
        u32x2 val = *(const u32x2*)&tb[d * 68 + so];  // 8B, aligned (68*2=136%8==0)
        *(u32x2*)&C2[obase + (size_t)d * 2048 + s0 + so] = val;
      }
    }
  }
}

// ======== causal flash attention v5 (r17/r19-proven) ========
__global__ __launch_bounds__(256, 2) void k_attn(const bf16_t* __restrict__ q,
                                                 const bf16_t* __restrict__ kbuf,
                                                 const bf16_t* __restrict__ vT,
                                                 bf16_t* __restrict__ attn_out) {
  __shared__ alignas(16) char KsB[2][64 * 128];
  __shared__ alignas(16) char VtB[2][64 * 128];
  const int tid = threadIdx.x, lane = tid & 63, wave = tid >> 6;
  const int lane15 = lane & 15, g = lane >> 4;
  const int id = blockIdx.y * 16 + blockIdx.x;
  const int swz = (id & 7) * 128 + (id >> 3);
  const int bqx = swz & 15;
  const int bh = swz >> 4;
  const int b = bh >> 5, h = bh & 31;
  const size_t base = (size_t)bh * 2048 * 64;
  const size_t baseT = (size_t)bh * 64 * 2048;
  const float SC = 0.18033688f;
  const int srow = lane >> 3;
  const int swc = (lane & 7) ^ srow;

  auto stage = [&](int t, int buf) {
#pragma unroll
    for (int i = 0; i < 2; ++i) {
      int r = wave * 16 + i * 8;
      gload_lds16(&kbuf[base + (size_t)(t * 64 + r + srow) * 64 + swc * 8],
                  (bf16_t*)(KsB[buf] + r * 128));
      gload_lds16(&vT[baseT + (size_t)(r + srow) * 2048 + t * 64 + swc * 8],
                  (bf16_t*)(VtB[buf] + r * 128));
    }
  };

  for (int pass = 0; pass < 2; ++pass) {
    const int qb = pass == 0 ? (31 - bqx) : bqx;
    const int qg0 = qb * 64 + wave * 16;
    bf16x8 aq[2];
#pragma unroll
    for (int kk = 0; kk < 2; ++kk) {
      bf16x8 raw = *(const bf16x8*)&q[base + (size_t)(qg0 + lane15) * 64 + kk * 32 + g * 8];
      bf16x8 s8;
#pragma unroll
      for (int e = 0; e < 8; ++e) s8[e] = (bf16_t)((float)raw[e] * SC);
      aq[kk] = s8;
    }
    float m_r = -INFINITY, l_r = 0.f;
    f32x4 o[4] = {};

    stage(0, 0);
    __syncthreads();
    for (int t = 0; t <= qb; ++t) {
      const int buf = t & 1;
      const char* Kb = KsB[buf];
      const char* Vb = VtB[buf];
      if (t < qb) stage(t + 1, buf ^ 1);  // loads land during this tile's compute
      const bool diag = (t == qb);
      const int nlim = diag ? wave : 3;
      f32x4 sv[4];
#pragma unroll
      for (int n = 0; n < 4; ++n)
        if (n <= nlim) {
          f32x4 a = {};
#pragma unroll
          for (int kk = 0; kk < 2; ++kk) {
            int byt = ((n * 16 + lane15) * 128 + kk * 64 + g * 16) ^ ((lane15 & 7) << 4);
            a = MFMA16(*(const bf16x8*)(Kb + byt), aq[kk], a);
          }
          sv[n] = a;
          if (diag && n == wave) {
#pragma unroll
            for (int j = 0; j < 4; ++j)
              if (g * 4 + j > lane15) sv[n][j] = -1e30f;
          }
        }
      float mt = -1e30f;
#pragma unroll
      for (int n = 0; n < 4; ++n)
        if (n <= nlim)
#pragma unroll
          for (int j = 0; j < 4; ++j) mt = fmaxf(mt, sv[n][j]);
      mt = fmaxf(mt, __shfl_xor(mt, 16));
      mt = fmaxf(mt, __shfl_xor(mt, 32));
      if (!__all(mt <= m_r + 8.f)) {
        float mn = fmaxf(m_r, mt);
        float corr = exp2f(m_r - mn);
        float cb[4];
#pragma unroll
        for (int j = 0; j < 4; ++j) cb[j] = __shfl(corr, g * 4 + j);
#pragma unroll
        for (int f = 0; f < 4; ++f)
#pragma unroll
          for (int j = 0; j < 4; ++j) o[f][j] *= cb[j];
        l_r *= corr;
        m_r = mn;
      }
      float rs = 0.f;
      u32 pk[4][2];
#pragma unroll
      for (int n = 0; n < 4; ++n) {
        if (n <= nlim) {
          float p0 = exp2f(sv[n][0] - m_r);
          float p1 = exp2f(sv[n][1] - m_r);
          float p2 = exp2f(sv[n][2] - m_r);
          float p3 = exp2f(sv[n][3] - m_r);
          rs += (p0 + p1) + (p2 + p3);
          union { bf16x2 v; u32 u; } c0, c1;
          c0.v[0] = (bf16_t)p0; c0.v[1] = (bf16_t)p1;
          c1.v[0] = (bf16_t)p2; c1.v[1] = (bf16_t)p3;
          pk[n][0] = c0.u; pk[n][1] = c1.u;
        } else {
          pk[n][0] = 0u; pk[n][1] = 0u;
        }
      }
      rs += __shfl_xor(rs, 16);
      rs += __shfl_xor(rs, 32);
      l_r += rs;
      const int srcA = ((g & 1) << 5) + lane15;
      const int srcB = srcA + 16;
      const bool hi = (g >> 1) != 0;
#pragma unroll
      for (int kk = 0; kk < 2; ++kk)
        if (2 * kk <= nlim) {
          u32 a0 = __shfl(pk[2 * kk][0], srcA), b0 = __shfl(pk[2 * kk + 1][0], srcA);
          u32 a1 = __shfl(pk[2 * kk][1], srcA), b1 = __shfl(pk[2 * kk + 1][1], srcA);
          u32 a2 = __shfl(pk[2 * kk][0], srcB), b2 = __shfl(pk[2 * kk + 1][0], srcB);
          u32 a3 = __shfl(pk[2 * kk][1], srcB), b3 = __shfl(pk[2 * kk + 1][1], srcB);
          union { u32x4 u; bf16x8 v; } pa;
          pa.u[0] = hi ? b0 : a0;
          pa.u[1] = hi ? b1 : a1;
          pa.u[2] = hi ? b2 : a2;
          pa.u[3] = hi ? b3 : a3;
#pragma unroll
          for (int f = 0; f < 4; ++f) {
            int byt = ((f * 16 + lane15) * 128 + kk * 64 + g * 16) ^ ((lane15 & 7) << 4);
            bf16x8 bv = *(const bf16x8*)(Vb + byt);
            o[f] = MFMA16(pa.v, bv, o[f]);
          }
        }
      __syncthreads();
    }
    float lb[4];
#pragma unroll
    for (int j = 0; j < 4; ++j) lb[j] = __shfl(l_r, g * 4 + j);
#pragma unroll
    for (int f = 0; f < 4; ++f)
#pragma unroll
      for (int j = 0; j < 4; ++j) {
        int qg = qg0 + g * 4 + j;
        attn_out[(size_t)(b * 2048 + qg) * 2048 + h * 64 + f * 16 + lane15] =
            (bf16_t)(o[f][j] / lb[j]);
      }
  }
}

extern "C" void kernel_launch(void* const* d_in, const int* in_sizes, int n_in, void* d_out,
                              int out_size, void* d_ws, size_t ws_size, hipStream_t stream) {
  const float* x = (const float*)d_in[0];
  const float* Wqkv = (const float*)d_in[1];
  const float* bqkv = (const float*)d_in[2];
  const float* Wo = (const float*)d_in[3];
  const float* bo = (const float*)d_in[4];
  float* out = (float*)d_out;  // fp32 output

  char* ws = (char*)d_ws;
  size_t off = 0;
  auto carve = [&](size_t bytes) {
    void* p = ws + off;
    off += (bytes + 255) & ~(size_t)255;
    return p;
  };
  bf16_t* x_bf = (bf16_t*)carve((size_t)4096 * 2048 * 2);
  bf16_t* wqkv_t = (bf16_t*)carve((size_t)6144 * 2048 * 2);
  bf16_t* wo_t = (bf16_t*)carve((size_t)2048 * 2048 * 2);
  bf16_t* qb_ = (bf16_t*)carve((size_t)64 * 2048 * 64 * 2);
  bf16_t* kb_ = (bf16_t*)carve((size_t)64 * 2048 * 64 * 2);
  bf16_t* vbT = (bf16_t*)carve((size_t)64 * 64 * 2048 * 2);
  bf16_t* attn = (bf16_t*)carve((size_t)4096 * 2048 * 2);
  float* ct = (float*)carve((size_t)2048 * 16 * 4);
  float* st = (float*)carve((size_t)2048 * 16 * 4);
  if (off > ws_size) return;  // sentinel

  // allow 80KB dynamic LDS for the pipelined GEMMs (idempotent; rc ignored)
  (void)hipFuncSetAttribute((const void*)&k_gemm256<6144, 2048, 1, false>,
                            hipFuncAttributeMaxDynamicSharedMemorySize, 81920);
  (void)hipFuncSetAttribute((const void*)&k_gemm256<2048, 2048, 0, true>,
                            hipFuncAttributeMaxDynamicSharedMemorySize, 81920);

  k_cvt<<<2048, 256, 0, stream>>>(x, x_bf, 4096 * 2048);
  k_transpose_cvt<<<dim3(192, 64), dim3(32, 8), 0, stream>>>(Wqkv, wqkv_t, 2048, 6144);
  k_transpose_cvt<<<dim3(64, 64), dim3(32, 8), 0, stream>>>(Wo, wo_t, 2048, 2048);
  k_sincos<<<128, 256, 0, stream>>>(ct, st);
  // GEMM1: 48x32 = 1536 blocks = 3.0 rounds at 2 blk/CU; rope+split epilogue; V pre-transposed
  k_gemm256<6144, 2048, 1, false><<<dim3(48, 32), 256, 81920, stream>>>(
      x_bf, wqkv_t, bqkv, qb_, kb_, vbT, ct, st);
  k_attn<<<dim3(16, 64), 256, 0, stream>>>(qb_, kb_, vbT, attn);
  // GEMM2: 16x32 = 512 blocks = 1.0 round at 2 blk/CU, fp32 out
  k_gemm256<2048, 2048, 0, true><<<dim3(16, 32), 256, 81920, stream>>>(
      attn, wo_t, bo, out, nullptr, nullptr, nullptr, nullptr);
}

// Round 22
// 269.449 us; speedup vs baseline: 1.0168x; 1.0168x over previous
//
#include <hip/hip_runtime.h>
#include <hip/hip_bf16.h>
#include <math.h>

typedef __bf16 bf16_t;
typedef __bf16 bf16x8 __attribute__((ext_vector_type(8)));
typedef __bf16 bf16x2 __attribute__((ext_vector_type(2)));
typedef float f32x4 __attribute__((ext_vector_type(4)));
typedef unsigned int u32;
typedef u32 u32x4 __attribute__((ext_vector_type(4)));
typedef u32 u32x2 __attribute__((ext_vector_type(2)));

#define MFMA16(a,b,c) __builtin_amdgcn_mfma_f32_16x16x32_bf16((a),(b),(c),0,0,0)

// async global->LDS, 16B per lane; LDS dest = wave-uniform base + lane*16
__device__ __forceinline__ void gload_lds16(const bf16_t* g, bf16_t* l) {
  __builtin_amdgcn_global_load_lds(
      (const __attribute__((address_space(1))) void*)g,
      (__attribute__((address_space(3))) void*)l, 16, 0, 0);
}

// ---------------- fp32 -> bf16 flat convert (8/thread) ----------------
__global__ void k_cvt(const float* __restrict__ in, bf16_t* __restrict__ out, int n) {
  int i = (blockIdx.x * blockDim.x + threadIdx.x) * 8;
  int stride = gridDim.x * blockDim.x * 8;
  for (; i < n; i += stride) {
    float4 a = *(const float4*)&in[i];
    float4 b = *(const float4*)&in[i + 4];
    bf16x8 o;
    o[0] = (bf16_t)a.x; o[1] = (bf16_t)a.y; o[2] = (bf16_t)a.z; o[3] = (bf16_t)a.w;
    o[4] = (bf16_t)b.x; o[5] = (bf16_t)b.y; o[6] = (bf16_t)b.z; o[7] = (bf16_t)b.w;
    *(bf16x8*)&out[i] = o;
  }
}

// ---------------- fp32 [R][C] -> bf16 [C][R] transpose-convert ----------------
__global__ void k_transpose_cvt(const float* __restrict__ in, bf16_t* __restrict__ out,
                                int R, int C) {
  __shared__ float tile[32][33];
  int c0 = blockIdx.x * 32, r0 = blockIdx.y * 32;
  int x = threadIdx.x, y = threadIdx.y;  // block (32,8)
#pragma unroll
  for (int i = 0; i < 32; i += 8) tile[y + i][x] = in[(size_t)(r0 + y + i) * C + c0 + x];
  __syncthreads();
#pragma unroll
  for (int i = 0; i < 32; i += 8)
    out[(size_t)(c0 + y + i) * R + r0 + x] = (bf16_t)tile[x][y + i];
}

// ---------------- RoPE cos/sin table: [2048][16] each ----------------
__global__ void k_sincos(float* __restrict__ ct, float* __restrict__ st) {
  int idx = blockIdx.x * blockDim.x + threadIdx.x;  // 0..32767
  int pos = idx >> 4, i = idx & 15;
  float invf = powf(10000.0f, -(float)i / 16.0f);
  float ang = (float)pos * invf;
  ct[idx] = cosf(ang);
  st[idx] = sinf(ang);
}

// ======== 128x128-tile 2-phase counted-vmcnt GEMM (r20-proven: best measured config) ========
// 4 waves, LDS 64KB (A[2]@0/16K, B[2]@32K/48K) -> 2 blk/CU. 2 barriers/tile, vmcnt(4),
// all 16 frag reads hoisted to ph0. r21's deeper pipeline (triple-A, vmcnt(8)) REGRESSED
// (FETCH +13%, MfmaUtil -3) -> reverted to this.
// EPI=1: rope+head-split epilogue, V transposed via per-wave LDS tile. EPI=0: plain store.
template <int N, int K, int EPI, bool OUT_F32>
__global__ __launch_bounds__(256, 2) void k_gemm256(const bf16_t* __restrict__ A,
                                                    const bf16_t* __restrict__ Bt,
                                                    const float* __restrict__ bias,
                                                    void* __restrict__ C0,
                                                    bf16_t* __restrict__ C1,
                                                    bf16_t* __restrict__ C2,
                                                    const float* __restrict__ ct,
                                                    const float* __restrict__ st) {
  extern __shared__ char smem[];  // 65536 bytes
  const int tid = threadIdx.x, lane = tid & 63, w = tid >> 6;
  const int lane15 = lane & 15, g = lane >> 4;
  const int wr = w >> 1, wc = w & 1;
  const int rowBase = blockIdx.y * 128, colBase = blockIdx.x * 128;
  constexpr int NT = K / 64;
  const int srow = lane >> 3;            // 0..7 row within 8-row stripe
  const int schunk = (lane & 7) ^ srow;  // pre-swizzled source chunk
  const int rdswz = (lane15 & 7) << 4;   // read-side swizzle

  auto stageA = [&](int t) {  // A tile 128x64: 4 wave-loads (8 rows each)
    const bf16_t* gb = A + (size_t)rowBase * K + t * 64;
    char* lb = smem + (t & 1) * 16384;
#pragma unroll
    for (int i = 0; i < 4; ++i) {
      int r0 = (w * 4 + i) * 8;
      gload_lds16(gb + (size_t)(r0 + srow) * K + schunk * 8, (bf16_t*)(lb + r0 * 128));
    }
  };
  auto stageB = [&](int t) {  // B tile 128x64: 4 wave-loads
    const bf16_t* gb = Bt + (size_t)colBase * K + t * 64;
    char* lb = smem + 32768 + (t & 1) * 16384;
#pragma unroll
    for (int i = 0; i < 4; ++i) {
      int r0 = (w * 4 + i) * 8;
      gload_lds16(gb + (size_t)(r0 + srow) * K + schunk * 8, (bf16_t*)(lb + r0 * 128));
    }
  };

  f32x4 acc[4][4] = {};
  // prologue: B(0), A(0) [8 loads] + B(1) [4 loads in flight]
  stageB(0); stageA(0);
  stageB(1);
  asm volatile("s_waitcnt vmcnt(4)" ::: "memory");
  __builtin_amdgcn_sched_barrier(0);
  __builtin_amdgcn_s_barrier();

  for (int t = 0; t < NT; ++t) {
    const char* ab = smem + (t & 1) * 16384;
    const char* bb = smem + 32768 + (t & 1) * 16384;
    bf16x8 bfr[4][2], af[4][2];
    // ---- phase 0: ALL frag reads (8 B + 8 A); stage A(t+1); MFMA m0,m1; BAR ----
#pragma unroll
    for (int n = 0; n < 4; ++n)
#pragma unroll
      for (int kk = 0; kk < 2; ++kk)
        bfr[n][kk] = *(const bf16x8*)(bb + (wc * 64 + n * 16 + lane15) * 128 +
                                      ((kk * 64 + g * 16) ^ rdswz));
#pragma unroll
    for (int mi = 0; mi < 4; ++mi)
#pragma unroll
      for (int kk = 0; kk < 2; ++kk)
        af[mi][kk] = *(const bf16x8*)(ab + (wr * 64 + mi * 16 + lane15) * 128 +
                                      ((kk * 64 + g * 16) ^ rdswz));
    if (t + 1 < NT) stageA(t + 1);
    __builtin_amdgcn_s_setprio(1);
#pragma unroll
    for (int mi = 0; mi < 2; ++mi)
#pragma unroll
      for (int n = 0; n < 4; ++n)
#pragma unroll
        for (int kk = 0; kk < 2; ++kk)
          acc[mi][n] = MFMA16(af[mi][kk], bfr[n][kk], acc[mi][n]);
    __builtin_amdgcn_s_setprio(0);
    __builtin_amdgcn_s_barrier();
    // ---- phase 1: stage B(t+2); MFMA m2,m3 (frags already in regs); vmcnt(4); BAR ----
    if (t + 2 < NT) stageB(t + 2);
    __builtin_amdgcn_s_setprio(1);
#pragma unroll
    for (int mi = 2; mi < 4; ++mi)
#pragma unroll
      for (int n = 0; n < 4; ++n)
#pragma unroll
        for (int kk = 0; kk < 2; ++kk)
          acc[mi][n] = MFMA16(af[mi][kk], bfr[n][kk], acc[mi][n]);
    __builtin_amdgcn_s_setprio(0);
    if (t + 2 < NT) {
      asm volatile("s_waitcnt vmcnt(4)" ::: "memory");
    } else {
      asm volatile("s_waitcnt vmcnt(0)" ::: "memory");
    }
    __builtin_amdgcn_sched_barrier(0);
    __builtin_amdgcn_s_barrier();
  }

  if constexpr (EPI == 0) {
#pragma unroll
    for (int m = 0; m < 4; ++m)
#pragma unroll
      for (int n = 0; n < 4; ++n) {
        int ccol = colBase + wc * 64 + n * 16 + lane15;
        float bb2 = bias[ccol];
#pragma unroll
        for (int j = 0; j < 4; ++j) {
          int crow = rowBase + wr * 64 + m * 16 + g * 4 + j;
          if constexpr (OUT_F32)
            ((float*)C0)[(size_t)crow * N + ccol] = acc[m][n][j] + bb2;
          else
            ((bf16_t*)C0)[(size_t)crow * N + ccol] = (bf16_t)(acc[m][n][j] + bb2);
        }
      }
  } else {
    const int colb = colBase + wc * 64;
    const int which = colb >> 11;  // 0=q 1=k 2=v (wave-uniform)
    const int h = (colb >> 6) & 31;
    float bb2[4];
#pragma unroll
    for (int n = 0; n < 4; ++n) bb2[n] = bias[colb + n * 16 + lane15];
    if (which < 2) {
      // q/k: rope + row-major store [bh][s][64]
      bf16_t* dst = which == 0 ? (bf16_t*)C0 : C1;
#pragma unroll
      for (int m = 0; m < 4; ++m)
#pragma unroll
        for (int j = 0; j < 4; ++j) {
          int row = rowBase + wr * 64 + m * 16 + g * 4 + j;
          int s = row & 2047, b = row >> 11;
          float v[4];
#pragma unroll
          for (int n = 0; n < 4; ++n) v[n] = acc[m][n][j] + bb2[n];
          float c = ct[s * 16 + lane15], sn = st[s * 16 + lane15];
          float a = v[0], b2 = v[1];
          v[0] = a * c - b2 * sn;
          v[1] = a * sn + b2 * c;
          bf16_t* drow = dst + ((size_t)(b * 32 + h) * 2048 + s) * 64;
#pragma unroll
          for (int n = 0; n < 4; ++n) drow[n * 16 + lane15] = (bf16_t)v[n];
        }
    } else {
      // V: transpose via per-wave private LDS tile [64 d][68 s], write vT [bh][64][2048]
      bf16_t* tb = (bf16_t*)(smem + w * 8704);
#pragma unroll
      for (int m = 0; m < 4; ++m)
#pragma unroll
        for (int j = 0; j < 4; ++j) {
          int sl = m * 16 + g * 4 + j;
#pragma unroll
          for (int n = 0; n < 4; ++n)
            tb[(n * 16 + lane15) * 68 + sl] = (bf16_t)(acc[m][n][j] + bb2[n]);
        }
      asm volatile("s_waitcnt lgkmcnt(0)" ::: "memory");
      __builtin_amdgcn_sched_barrier(0);
      const int row0 = rowBase + wr * 64;  // 64-row range never crosses batch boundary
      const int s0 = row0 & 2047, b = row0 >> 11;
      const size_t obase = (size_t)(b * 32 + h) * 64 * 2048;
#pragma unroll
      for (int i = 0; i < 16; ++i) {
        int d = i * 4 + (lane >> 4);
        int so = lane15 * 4;
        u32x2 val = *(const u32x2*)&tb[d * 68 + so];  // 8B, aligned (68*2=136%8==0)
        *(u32x2*)&C2[obase + (size_t)d * 2048 + s0 + so] = val;
      }
    }
  }
}

// ======== causal flash attention v5 (r17/r19/r20-proven) ========
__global__ __launch_bounds__(256, 2) void k_attn(const bf16_t* __restrict__ q,
                                                 const bf16_t* __restrict__ kbuf,
                                                 const bf16_t* __restrict__ vT,
                                                 bf16_t* __restrict__ attn_out) {
  __shared__ alignas(16) char KsB[2][64 * 128];
  __shared__ alignas(16) char VtB[2][64 * 128];
  const int tid = threadIdx.x, lane = tid & 63, wave = tid >> 6;
  const int lane15 = lane & 15, g = lane >> 4;
  const int id = blockIdx.y * 16 + blockIdx.x;
  const int swz = (id & 7) * 128 + (id >> 3);
  const int bqx = swz & 15;
  const int bh = swz >> 4;
  const int b = bh >> 5, h = bh & 31;
  const size_t base = (size_t)bh * 2048 * 64;
  const size_t baseT = (size_t)bh * 64 * 2048;
  const float SC = 0.18033688f;
  const int srow = lane >> 3;
  const int swc = (lane & 7) ^ srow;

  auto stage = [&](int t, int buf) {
#pragma unroll
    for (int i = 0; i < 2; ++i) {
      int r = wave * 16 + i * 8;
      gload_lds16(&kbuf[base + (size_t)(t * 64 + r + srow) * 64 + swc * 8],
                  (bf16_t*)(KsB[buf] + r * 128));
      gload_lds16(&vT[baseT + (size_t)(r + srow) * 2048 + t * 64 + swc * 8],
                  (bf16_t*)(VtB[buf] + r * 128));
    }
  };

  for (int pass = 0; pass < 2; ++pass) {
    const int qb = pass == 0 ? (31 - bqx) : bqx;
    const int qg0 = qb * 64 + wave * 16;
    bf16x8 aq[2];
#pragma unroll
    for (int kk = 0; kk < 2; ++kk) {
      bf16x8 raw = *(const bf16x8*)&q[base + (size_t)(qg0 + lane15) * 64 + kk * 32 + g * 8];
      bf16x8 s8;
#pragma unroll
      for (int e = 0; e < 8; ++e) s8[e] = (bf16_t)((float)raw[e] * SC);
      aq[kk] = s8;
    }
    float m_r = -INFINITY, l_r = 0.f;
    f32x4 o[4] = {};

    stage(0, 0);
    __syncthreads();
    for (int t = 0; t <= qb; ++t) {
      const int buf = t & 1;
      const char* Kb = KsB[buf];
      const char* Vb = VtB[buf];
      if (t < qb) stage(t + 1, buf ^ 1);  // loads land during this tile's compute
      const bool diag = (t == qb);
      const int nlim = diag ? wave : 3;
      f32x4 sv[4];
#pragma unroll
      for (int n = 0; n < 4; ++n)
        if (n <= nlim) {
          f32x4 a = {};
#pragma unroll
          for (int kk = 0; kk < 2; ++kk) {
            int byt = ((n * 16 + lane15) * 128 + kk * 64 + g * 16) ^ ((lane15 & 7) << 4);
            a = MFMA16(*(const bf16x8*)(Kb + byt), aq[kk], a);
          }
          sv[n] = a;
          if (diag && n == wave) {
#pragma unroll
            for (int j = 0; j < 4; ++j)
              if (g * 4 + j > lane15) sv[n][j] = -1e30f;
          }
        }
      float mt = -1e30f;
#pragma unroll
      for (int n = 0; n < 4; ++n)
        if (n <= nlim)
#pragma unroll
          for (int j = 0; j < 4; ++j) mt = fmaxf(mt, sv[n][j]);
      mt = fmaxf(mt, __shfl_xor(mt, 16));
      mt = fmaxf(mt, __shfl_xor(mt, 32));
      if (!__all(mt <= m_r + 8.f)) {
        float mn = fmaxf(m_r, mt);
        float corr = exp2f(m_r - mn);
        float cb[4];
#pragma unroll
        for (int j = 0; j < 4; ++j) cb[j] = __shfl(corr, g * 4 + j);
#pragma unroll
        for (int f = 0; f < 4; ++f)
#pragma unroll
          for (int j = 0; j < 4; ++j) o[f][j] *= cb[j];
        l_r *= corr;
        m_r = mn;
      }
      float rs = 0.f;
      u32 pk[4][2];
#pragma unroll
      for (int n = 0; n < 4; ++n) {
        if (n <= nlim) {
          float p0 = exp2f(sv[n][0] - m_r);
          float p1 = exp2f(sv[n][1] - m_r);
          float p2 = exp2f(sv[n][2] - m_r);
          float p3 = exp2f(sv[n][3] - m_r);
          rs += (p0 + p1) + (p2 + p3);
          union { bf16x2 v; u32 u; } c0, c1;
          c0.v[0] = (bf16_t)p0; c0.v[1] = (bf16_t)p1;
          c1.v[0] = (bf16_t)p2; c1.v[1] = (bf16_t)p3;
          pk[n][0] = c0.u; pk[n][1] = c1.u;
        } else {
          pk[n][0] = 0u; pk[n][1] = 0u;
        }
      }
      rs += __shfl_xor(rs, 16);
      rs += __shfl_xor(rs, 32);
      l_r += rs;
      const int srcA = ((g & 1) << 5) + lane15;
      const int srcB = srcA + 16;
      const bool hi = (g >> 1) != 0;
#pragma unroll
      for (int kk = 0; kk < 2; ++kk)
        if (2 * kk <= nlim) {
          u32 a0 = __shfl(pk[2 * kk][0], srcA), b0 = __shfl(pk[2 * kk + 1][0], srcA);
          u32 a1 = __shfl(pk[2 * kk][1], srcA), b1 = __shfl(pk[2 * kk + 1][1], srcA);
          u32 a2 = __shfl(pk[2 * kk][0], srcB), b2 = __shfl(pk[2 * kk + 1][0], srcB);
          u32 a3 = __shfl(pk[2 * kk][1], srcB), b3 = __shfl(pk[2 * kk + 1][1], srcB);
          union { u32x4 u; bf16x8 v; } pa;
          pa.u[0] = hi ? b0 : a0;
          pa.u[1] = hi ? b1 : a1;
          pa.u[2] = hi ? b2 : a2;
          pa.u[3] = hi ? b3 : a3;
#pragma unroll
          for (int f = 0; f < 4; ++f) {
            int byt = ((f * 16 + lane15) * 128 + kk * 64 + g * 16) ^ ((lane15 & 7) << 4);
            bf16x8 bv = *(const bf16x8*)(Vb + byt);
            o[f] = MFMA16(pa.v, bv, o[f]);
          }
        }
      __syncthreads();
    }
    float lb[4];
#pragma unroll
    for (int j = 0; j < 4; ++j) lb[j] = __shfl(l_r, g * 4 + j);
#pragma unroll
    for (int f = 0; f < 4; ++f)
#pragma unroll
      for (int j = 0; j < 4; ++j) {
        int qg = qg0 + g * 4 + j;
        attn_out[(size_t)(b * 2048 + qg) * 2048 + h * 64 + f * 16 + lane15] =
            (bf16_t)(o[f][j] / lb[j]);
      }
  }
}

extern "C" void kernel_launch(void* const* d_in, const int* in_sizes, int n_in, void* d_out,
                              int out_size, void* d_ws, size_t ws_size, hipStream_t stream) {
  const float* x = (const float*)d_in[0];
  const float* Wqkv = (const float*)d_in[1];
  const float* bqkv = (const float*)d_in[2];
  const float* Wo = (const float*)d_in[3];
  const float* bo = (const float*)d_in[4];
  float* out = (float*)d_out;  // fp32 output

  char* ws = (char*)d_ws;
  size_t off = 0;
  auto carve = [&](size_t bytes) {
    void* p = ws + off;
    off += (bytes + 255) & ~(size_t)255;
    return p;
  };
  bf16_t* x_bf = (bf16_t*)carve((size_t)4096 * 2048 * 2);
  bf16_t* wqkv_t = (bf16_t*)carve((size_t)6144 * 2048 * 2);
  bf16_t* wo_t = (bf16_t*)carve((size_t)2048 * 2048 * 2);
  bf16_t* qb_ = (bf16_t*)carve((size_t)64 * 2048 * 64 * 2);
  bf16_t* kb_ = (bf16_t*)carve((size_t)64 * 2048 * 64 * 2);
  bf16_t* vbT = (bf16_t*)carve((size_t)64 * 64 * 2048 * 2);
  bf16_t* attn = (bf16_t*)carve((size_t)4096 * 2048 * 2);
  float* ct = (float*)carve((size_t)2048 * 16 * 4);
  float* st = (float*)carve((size_t)2048 * 16 * 4);
  if (off > ws_size) return;  // sentinel

  // allow 64KB dynamic LDS for the pipelined GEMMs (idempotent; rc ignored)
  (void)hipFuncSetAttribute((const void*)&k_gemm256<6144, 2048, 1, false>,
                            hipFuncAttributeMaxDynamicSharedMemorySize, 65536);
  (void)hipFuncSetAttribute((const void*)&k_gemm256<2048, 2048, 0, true>,
                            hipFuncAttributeMaxDynamicSharedMemorySize, 65536);

  k_cvt<<<2048, 256, 0, stream>>>(x, x_bf, 4096 * 2048);
  k_transpose_cvt<<<dim3(192, 64), dim3(32, 8), 0, stream>>>(Wqkv, wqkv_t, 2048, 6144);
  k_transpose_cvt<<<dim3(64, 64), dim3(32, 8), 0, stream>>>(Wo, wo_t, 2048, 2048);
  k_sincos<<<128, 256, 0, stream>>>(ct, st);
  // GEMM1: 48x32 = 1536 blocks = 3.0 rounds at 2 blk/CU; rope+split epilogue; V pre-transposed
  k_gemm256<6144, 2048, 1, false><<<dim3(48, 32), 256, 65536, stream>>>(
      x_bf, wqkv_t, bqkv, qb_, kb_, vbT, ct, st);
  k_attn<<<dim3(16, 64), 256, 0, stream>>>(qb_, kb_, vbT, attn);
  // GEMM2: 16x32 = 512 blocks = 1.0 round at 2 blk/CU, fp32 out
  k_gemm256<2048, 2048, 0, true><<<dim3(16, 32), 256, 65536, stream>>>(
      attn, wo_t, bo, out, nullptr, nullptr, nullptr, nullptr);
}

// Round 23
// 262.727 us; speedup vs baseline: 1.0429x; 1.0256x over previous
//
#include <hip/hip_runtime.h>
#include <hip/hip_bf16.h>
#include <math.h>

typedef __bf16 bf16_t;
typedef __bf16 bf16x8 __attribute__((ext_vector_type(8)));
typedef __bf16 bf16x2 __attribute__((ext_vector_type(2)));
typedef float f32x4 __attribute__((ext_vector_type(4)));
typedef unsigned int u32;
typedef u32 u32x4 __attribute__((ext_vector_type(4)));
typedef u32 u32x2 __attribute__((ext_vector_type(2)));

#define MFMA16(a,b,c) __builtin_amdgcn_mfma_f32_16x16x32_bf16((a),(b),(c),0,0,0)

// async global->LDS, 16B per lane; LDS dest = wave-uniform base + lane*16
__device__ __forceinline__ void gload_lds16(const bf16_t* g, bf16_t* l) {
  __builtin_amdgcn_global_load_lds(
      (const __attribute__((address_space(1))) void*)g,
      (__attribute__((address_space(3))) void*)l, 16, 0, 0);
}

// ======== merged prep: fp32->bf16 cvt + 2 transpose-cvts + sincos, one dispatch ========
// Block ranges (all branches block-uniform -> __syncthreads legal):
//   [0,1024)              : x fp32->bf16, grid-stride over 4096*2048 elems
//   [1024,13312)          : Wqkv [2048][6144] -> wqkv_t [6144][2048] bf16  (192x64 tiles)
//   [13312,17408)         : Wo   [2048][2048] -> wo_t   [2048][2048] bf16  (64x64 tiles)
//   [17408,17536)         : rope cos/sin tables [2048][16]
__device__ __forceinline__ void transpose_tile(const float* __restrict__ in,
                                               bf16_t* __restrict__ out, int R, int C,
                                               int bx, int by, int tid) {
  __shared__ float tile[32][33];
  int c0 = bx * 32, r0 = by * 32;
  int x = tid & 31, y = tid >> 5;  // (32,8)
#pragma unroll
  for (int i = 0; i < 32; i += 8) tile[y + i][x] = in[(size_t)(r0 + y + i) * C + c0 + x];
  __syncthreads();
#pragma unroll
  for (int i = 0; i < 32; i += 8)
    out[(size_t)(c0 + y + i) * R + r0 + x] = (bf16_t)tile[x][y + i];
}

__global__ void k_prep(const float* __restrict__ x, bf16_t* __restrict__ x_bf,
                       const float* __restrict__ Wqkv, bf16_t* __restrict__ wqkv_t,
                       const float* __restrict__ Wo, bf16_t* __restrict__ wo_t,
                       float* __restrict__ ct, float* __restrict__ st) {
  const int bid = blockIdx.x, tid = threadIdx.x;
  if (bid < 1024) {
    int i = (bid * 256 + tid) * 8;
    const int stride = 1024 * 256 * 8;
    for (; i < 4096 * 2048; i += stride) {
      float4 a = *(const float4*)&x[i];
      float4 b = *(const float4*)&x[i + 4];
      bf16x8 o;
      o[0] = (bf16_t)a.x; o[1] = (bf16_t)a.y; o[2] = (bf16_t)a.z; o[3] = (bf16_t)a.w;
      o[4] = (bf16_t)b.x; o[5] = (bf16_t)b.y; o[6] = (bf16_t)b.z; o[7] = (bf16_t)b.w;
      *(bf16x8*)&x_bf[i] = o;
    }
  } else if (bid < 13312) {
    int id = bid - 1024;
    transpose_tile(Wqkv, wqkv_t, 2048, 6144, id % 192, id / 192, tid);
  } else if (bid < 17408) {
    int id = bid - 13312;
    transpose_tile(Wo, wo_t, 2048, 2048, id % 64, id / 64, tid);
  } else {
    int idx = (bid - 17408) * 256 + tid;  // 0..32767
    int pos = idx >> 4, i = idx & 15;
    float invf = powf(10000.0f, -(float)i / 16.0f);
    float ang = (float)pos * invf;
    ct[idx] = cosf(ang);
    st[idx] = sinf(ang);
  }
}

// ======== 128x128-tile 2-phase counted-vmcnt GEMM (r20/r22-proven: best measured config) ========
// 4 waves, LDS 64KB (A[2]@0/16K, B[2]@32K/48K) -> 2 blk/CU. 2 barriers/tile, vmcnt(4),
// all 16 frag reads hoisted to ph0.
// EPI=1: rope+head-split epilogue, V transposed via per-wave LDS tile. EPI=0: plain store.
template <int N, int K, int EPI, bool OUT_F32>
__global__ __launch_bounds__(256, 2) void k_gemm256(const bf16_t* __restrict__ A,
                                                    const bf16_t* __restrict__ Bt,
                                                    const float* __restrict__ bias,
                                                    void* __restrict__ C0,
                                                    bf16_t* __restrict__ C1,
                                                    bf16_t* __restrict__ C2,
                                                    const float* __restrict__ ct,
                                                    const float* __restrict__ st) {
  extern __shared__ char smem[];  // 65536 bytes
  const int tid = threadIdx.x, lane = tid & 63, w = tid >> 6;
  const int lane15 = lane & 15, g = lane >> 4;
  const int wr = w >> 1, wc = w & 1;
  const int rowBase = blockIdx.y * 128, colBase = blockIdx.x * 128;
  constexpr int NT = K / 64;
  const int srow = lane >> 3;            // 0..7 row within 8-row stripe
  const int schunk = (lane & 7) ^ srow;  // pre-swizzled source chunk
  const int rdswz = (lane15 & 7) << 4;   // read-side swizzle

  auto stageA = [&](int t) {  // A tile 128x64: 4 wave-loads (8 rows each)
    const bf16_t* gb = A + (size_t)rowBase * K + t * 64;
    char* lb = smem + (t & 1) * 16384;
#pragma unroll
    for (int i = 0; i < 4; ++i) {
      int r0 = (w * 4 + i) * 8;
      gload_lds16(gb + (size_t)(r0 + srow) * K + schunk * 8, (bf16_t*)(lb + r0 * 128));
    }
  };
  auto stageB = [&](int t) {  // B tile 128x64: 4 wave-loads
    const bf16_t* gb = Bt + (size_t)colBase * K + t * 64;
    char* lb = smem + 32768 + (t & 1) * 16384;
#pragma unroll
    for (int i = 0; i < 4; ++i) {
      int r0 = (w * 4 + i) * 8;
      gload_lds16(gb + (size_t)(r0 + srow) * K + schunk * 8, (bf16_t*)(lb + r0 * 128));
    }
  };

  f32x4 acc[4][4] = {};
  // prologue: B(0), A(0) [8 loads] + B(1) [4 loads in flight]
  stageB(0); stageA(0);
  stageB(1);
  asm volatile("s_waitcnt vmcnt(4)" ::: "memory");
  __builtin_amdgcn_sched_barrier(0);
  __builtin_amdgcn_s_barrier();

  for (int t = 0; t < NT; ++t) {
    const char* ab = smem + (t & 1) * 16384;
    const char* bb = smem + 32768 + (t & 1) * 16384;
    bf16x8 bfr[4][2], af[4][2];
    // ---- phase 0: ALL frag reads (8 B + 8 A); stage A(t+1); MFMA m0,m1; BAR ----
#pragma unroll
    for (int n = 0; n < 4; ++n)
#pragma unroll
      for (int kk = 0; kk < 2; ++kk)
        bfr[n][kk] = *(const bf16x8*)(bb + (wc * 64 + n * 16 + lane15) * 128 +
                                      ((kk * 64 + g * 16) ^ rdswz));
#pragma unroll
    for (int mi = 0; mi < 4; ++mi)
#pragma unroll
      for (int kk = 0; kk < 2; ++kk)
        af[mi][kk] = *(const bf16x8*)(ab + (wr * 64 + mi * 16 + lane15) * 128 +
                                      ((kk * 64 + g * 16) ^ rdswz));
    if (t + 1 < NT) stageA(t + 1);
    __builtin_amdgcn_s_setprio(1);
#pragma unroll
    for (int mi = 0; mi < 2; ++mi)
#pragma unroll
      for (int n = 0; n < 4; ++n)
#pragma unroll
        for (int kk = 0; kk < 2; ++kk)
          acc[mi][n] = MFMA16(af[mi][kk], bfr[n][kk], acc[mi][n]);
    __builtin_amdgcn_s_setprio(0);
    __builtin_amdgcn_s_barrier();
    // ---- phase 1: stage B(t+2); MFMA m2,m3 (frags already in regs); vmcnt(4); BAR ----
    if (t + 2 < NT) stageB(t + 2);
    __builtin_amdgcn_s_setprio(1);
#pragma unroll
    for (int mi = 2; mi < 4; ++mi)
#pragma unroll
      for (int n = 0; n < 4; ++n)
#pragma unroll
        for (int kk = 0; kk < 2; ++kk)
          acc[mi][n] = MFMA16(af[mi][kk], bfr[n][kk], acc[mi][n]);
    __builtin_amdgcn_s_setprio(0);
    if (t + 2 < NT) {
      asm volatile("s_waitcnt vmcnt(4)" ::: "memory");
    } else {
      asm volatile("s_waitcnt vmcnt(0)" ::: "memory");
    }
    __builtin_amdgcn_sched_barrier(0);
    __builtin_amdgcn_s_barrier();
  }

  if constexpr (EPI == 0) {
#pragma unroll
    for (int m = 0; m < 4; ++m)
#pragma unroll
      for (int n = 0; n < 4; ++n) {
        int ccol = colBase + wc * 64 + n * 16 + lane15;
        float bb2 = bias[ccol];
#pragma unroll
        for (int j = 0; j < 4; ++j) {
          int crow = rowBase + wr * 64 + m * 16 + g * 4 + j;
          if constexpr (OUT_F32)
            ((float*)C0)[(size_t)crow * N + ccol] = acc[m][n][j] + bb2;
          else
            ((bf16_t*)C0)[(size_t)crow * N + ccol] = (bf16_t)(acc[m][n][j] + bb2);
        }
      }
  } else {
    const int colb = colBase + wc * 64;
    const int which = colb >> 11;  // 0=q 1=k 2=v (wave-uniform)
    const int h = (colb >> 6) & 31;
    float bb2[4];
#pragma unroll
    for (int n = 0; n < 4; ++n) bb2[n] = bias[colb + n * 16 + lane15];
    if (which < 2) {
      // q/k: rope + row-major store [bh][s][64]
      bf16_t* dst = which == 0 ? (bf16_t*)C0 : C1;
#pragma unroll
      for (int m = 0; m < 4; ++m)
#pragma unroll
        for (int j = 0; j < 4; ++j) {
          int row = rowBase + wr * 64 + m * 16 + g * 4 + j;
          int s = row & 2047, b = row >> 11;
          float v[4];
#pragma unroll
          for (int n = 0; n < 4; ++n) v[n] = acc[m][n][j] + bb2[n];
          float c = ct[s * 16 + lane15], sn = st[s * 16 + lane15];
          float a = v[0], b2 = v[1];
          v[0] = a * c - b2 * sn;
          v[1] = a * sn + b2 * c;
          bf16_t* drow = dst + ((size_t)(b * 32 + h) * 2048 + s) * 64;
#pragma unroll
          for (int n = 0; n < 4; ++n) drow[n * 16 + lane15] = (bf16_t)v[n];
        }
    } else {
      // V: transpose via per-wave private LDS tile [64 d][68 s], write vT [bh][64][2048]
      bf16_t* tb = (bf16_t*)(smem + w * 8704);
#pragma unroll
      for (int m = 0; m < 4; ++m)
#pragma unroll
        for (int j = 0; j < 4; ++j) {
          int sl = m * 16 + g * 4 + j;
#pragma unroll
          for (int n = 0; n < 4; ++n)
            tb[(n * 16 + lane15) * 68 + sl] = (bf16_t)(acc[m][n][j] + bb2[n]);
        }
      asm volatile("s_waitcnt lgkmcnt(0)" ::: "memory");
      __builtin_amdgcn_sched_barrier(0);
      const int row0 = rowBase + wr * 64;  // 64-row range never crosses batch boundary
      const int s0 = row0 & 2047, b = row0 >> 11;
      const size_t obase = (size_t)(b * 32 + h) * 64 * 2048;
#pragma unroll
      for (int i = 0; i < 16; ++i) {
        int d = i * 4 + (lane >> 4);
        int so = lane15 * 4;
        u32x2 val = *(const u32x2*)&tb[d * 68 + so];  // 8B, aligned (68*2=136%8==0)
        *(u32x2*)&C2[obase + (size_t)d * 2048 + s0 + so] = val;
      }
    }
  }
}

// ======== causal flash attention v5 (r17/r19/r20/r22-proven) ========
__global__ __launch_bounds__(256, 2) void k_attn(const bf16_t* __restrict__ q,
                                                 const bf16_t* __restrict__ kbuf,
                                                 const bf16_t* __restrict__ vT,
                                                 bf16_t* __restrict__ attn_out) {
  __shared__ alignas(16) char KsB[2][64 * 128];
  __shared__ alignas(16) char VtB[2][64 * 128];
  const int tid = threadIdx.x, lane = tid & 63, wave = tid >> 6;
  const int lane15 = lane & 15, g = lane >> 4;
  const int id = blockIdx.y * 16 + blockIdx.x;
  const int swz = (id & 7) * 128 + (id >> 3);
  const int bqx = swz & 15;
  const int bh = swz >> 4;
  const int b = bh >> 5, h = bh & 31;
  const size_t base = (size_t)bh * 2048 * 64;
  const size_t baseT = (size_t)bh * 64 * 2048;
  const float SC = 0.18033688f;
  const int srow = lane >> 3;
  const int swc = (lane & 7) ^ srow;

  auto stage = [&](int t, int buf) {
#pragma unroll
    for (int i = 0; i < 2; ++i) {
      int r = wave * 16 + i * 8;
      gload_lds16(&kbuf[base + (size_t)(t * 64 + r + srow) * 64 + swc * 8],
                  (bf16_t*)(KsB[buf] + r * 128));
      gload_lds16(&vT[baseT + (size_t)(r + srow) * 2048 + t * 64 + swc * 8],
                  (bf16_t*)(VtB[buf] + r * 128));
    }
  };

  for (int pass = 0; pass < 2; ++pass) {
    const int qb = pass == 0 ? (31 - bqx) : bqx;
    const int qg0 = qb * 64 + wave * 16;
    bf16x8 aq[2];
#pragma unroll
    for (int kk = 0; kk < 2; ++kk) {
      bf16x8 raw = *(const bf16x8*)&q[base + (size_t)(qg0 + lane15) * 64 + kk * 32 + g * 8];
      bf16x8 s8;
#pragma unroll
      for (int e = 0; e < 8; ++e) s8[e] = (bf16_t)((float)raw[e] * SC);
      aq[kk] = s8;
    }
    float m_r = -INFINITY, l_r = 0.f;
    f32x4 o[4] = {};

    stage(0, 0);
    __syncthreads();
    for (int t = 0; t <= qb; ++t) {
      const int buf = t & 1;
      const char* Kb = KsB[buf];
      const char* Vb = VtB[buf];
      if (t < qb) stage(t + 1, buf ^ 1);  // loads land during this tile's compute
      const bool diag = (t == qb);
      const int nlim = diag ? wave : 3;
      f32x4 sv[4];
#pragma unroll
      for (int n = 0; n < 4; ++n)
        if (n <= nlim) {
          f32x4 a = {};
#pragma unroll
          for (int kk = 0; kk < 2; ++kk) {
            int byt = ((n * 16 + lane15) * 128 + kk * 64 + g * 16) ^ ((lane15 & 7) << 4);
            a = MFMA16(*(const bf16x8*)(Kb + byt), aq[kk], a);
          }
          sv[n] = a;
          if (diag && n == wave) {
#pragma unroll
            for (int j = 0; j < 4; ++j)
              if (g * 4 + j > lane15) sv[n][j] = -1e30f;
          }
        }
      float mt = -1e30f;
#pragma unroll
      for (int n = 0; n < 4; ++n)
        if (n <= nlim)
#pragma unroll
          for (int j = 0; j < 4; ++j) mt = fmaxf(mt, sv[n][j]);
      mt = fmaxf(mt, __shfl_xor(mt, 16));
      mt = fmaxf(mt, __shfl_xor(mt, 32));
      if (!__all(mt <= m_r + 8.f)) {
        float mn = fmaxf(m_r, mt);
        float corr = exp2f(m_r - mn);
        float cb[4];
#pragma unroll
        for (int j = 0; j < 4; ++j) cb[j] = __shfl(corr, g * 4 + j);
#pragma unroll
        for (int f = 0; f < 4; ++f)
#pragma unroll
          for (int j = 0; j < 4; ++j) o[f][j] *= cb[j];
        l_r *= corr;
        m_r = mn;
      }
      float rs = 0.f;
      u32 pk[4][2];
#pragma unroll
      for (int n = 0; n < 4; ++n) {
        if (n <= nlim) {
          float p0 = exp2f(sv[n][0] - m_r);
          float p1 = exp2f(sv[n][1] - m_r);
          float p2 = exp2f(sv[n][2] - m_r);
          float p3 = exp2f(sv[n][3] - m_r);
          rs += (p0 + p1) + (p2 + p3);
          union { bf16x2 v; u32 u; } c0, c1;
          c0.v[0] = (bf16_t)p0; c0.v[1] = (bf16_t)p1;
          c1.v[0] = (bf16_t)p2; c1.v[1] = (bf16_t)p3;
          pk[n][0] = c0.u; pk[n][1] = c1.u;
        } else {
          pk[n][0] = 0u; pk[n][1] = 0u;
        }
      }
      rs += __shfl_xor(rs, 16);
      rs += __shfl_xor(rs, 32);
      l_r += rs;
      const int srcA = ((g & 1) << 5) + lane15;
      const int srcB = srcA + 16;
      const bool hi = (g >> 1) != 0;
#pragma unroll
      for (int kk = 0; kk < 2; ++kk)
        if (2 * kk <= nlim) {
          u32 a0 = __shfl(pk[2 * kk][0], srcA), b0 = __shfl(pk[2 * kk + 1][0], srcA);
          u32 a1 = __shfl(pk[2 * kk][1], srcA), b1 = __shfl(pk[2 * kk + 1][1], srcA);
          u32 a2 = __shfl(pk[2 * kk][0], srcB), b2 = __shfl(pk[2 * kk + 1][0], srcB);
          u32 a3 = __shfl(pk[2 * kk][1], srcB), b3 = __shfl(pk[2 * kk + 1][1], srcB);
          union { u32x4 u; bf16x8 v; } pa;
          pa.u[0] = hi ? b0 : a0;
          pa.u[1] = hi ? b1 : a1;
          pa.u[2] = hi ? b2 : a2;
          pa.u[3] = hi ? b3 : a3;
#pragma unroll
          for (int f = 0; f < 4; ++f) {
            int byt = ((f * 16 + lane15) * 128 + kk * 64 + g * 16) ^ ((lane15 & 7) << 4);
            bf16x8 bv = *(const bf16x8*)(Vb + byt);
            o[f] = MFMA16(pa.v, bv, o[f]);
          }
        }
      __syncthreads();
    }
    float lb[4];
#pragma unroll
    for (int j = 0; j < 4; ++j) lb[j] = __shfl(l_r, g * 4 + j);
#pragma unroll
    for (int f = 0; f < 4; ++f)
#pragma unroll
      for (int j = 0; j < 4; ++j) {
        int qg = qg0 + g * 4 + j;
        attn_out[(size_t)(b * 2048 + qg) * 2048 + h * 64 + f * 16 + lane15] =
            (bf16_t)(o[f][j] / lb[j]);
      }
  }
}

extern "C" void kernel_launch(void* const* d_in, const int* in_sizes, int n_in, void* d_out,
                              int out_size, void* d_ws, size_t ws_size, hipStream_t stream) {
  const float* x = (const float*)d_in[0];
  const float* Wqkv = (const float*)d_in[1];
  const float* bqkv = (const float*)d_in[2];
  const float* Wo = (const float*)d_in[3];
  const float* bo = (const float*)d_in[4];
  float* out = (float*)d_out;  // fp32 output

  char* ws = (char*)d_ws;
  size_t off = 0;
  auto carve = [&](size_t bytes) {
    void* p = ws + off;
    off += (bytes + 255) & ~(size_t)255;
    return p;
  };
  bf16_t* x_bf = (bf16_t*)carve((size_t)4096 * 2048 * 2);
  bf16_t* wqkv_t = (bf16_t*)carve((size_t)6144 * 2048 * 2);
  bf16_t* wo_t = (bf16_t*)carve((size_t)2048 * 2048 * 2);
  bf16_t* qb_ = (bf16_t*)carve((size_t)64 * 2048 * 64 * 2);
  bf16_t* kb_ = (bf16_t*)carve((size_t)64 * 2048 * 64 * 2);
  bf16_t* vbT = (bf16_t*)carve((size_t)64 * 64 * 2048 * 2);
  bf16_t* attn = (bf16_t*)carve((size_t)4096 * 2048 * 2);
  float* ct = (float*)carve((size_t)2048 * 16 * 4);
  float* st = (float*)carve((size_t)2048 * 16 * 4);
  if (off > ws_size) return;  // sentinel

  // allow 64KB dynamic LDS for the pipelined GEMMs (idempotent; rc ignored)
  (void)hipFuncSetAttribute((const void*)&k_gemm256<6144, 2048, 1, false>,
                            hipFuncAttributeMaxDynamicSharedMemorySize, 65536);
  (void)hipFuncSetAttribute((const void*)&k_gemm256<2048, 2048, 0, true>,
                            hipFuncAttributeMaxDynamicSharedMemorySize, 65536);

  // merged prep (cvt + both weight transposes + rope tables) in ONE dispatch
  k_prep<<<17536, 256, 0, stream>>>(x, x_bf, Wqkv, wqkv_t, Wo, wo_t, ct, st);
  // GEMM1: 48x32 = 1536 blocks = 3.0 rounds at 2 blk/CU; rope+split epilogue; V pre-transposed
  k_gemm256<6144, 2048, 1, false><<<dim3(48, 32), 256, 65536, stream>>>(
      x_bf, wqkv_t, bqkv, qb_, kb_, vbT, ct, st);
  k_attn<<<dim3(16, 64), 256, 0, stream>>>(qb_, kb_, vbT, attn);
  // GEMM2: 16x32 = 512 blocks = 1.0 round at 2 blk/CU, fp32 out
  k_gemm256<2048, 2048, 0, true><<<dim3(16, 32), 256, 65536, stream>>>(
      attn, wo_t, bo, out, nullptr, nullptr, nullptr, nullptr);
}